// Round 1
// baseline (449.839 us; speedup 1.0000x reference)
//
#include <hip/hip_runtime.h>
#include <hip/hip_bf16.h>
#include <stdint.h>

// CrossAttnBlock: out = softmax((x Wq^T)(cond Wk^T)^T / 8) (cond Wv^T) Wo^T
// B=16 Lq=4096 Lk=77 D=512 Dc=768 H=8 Hd=64.
//
// R5 change: split fp32->bf16 conversion out of the GEMMs into a one-shot
// memory-bound pass (bf16 copies of x/cond/weights live in d_out used as
// scratch — it is dead until the final O-projection overwrites it). The
// GEMMs become pure-bf16 m97-structure: 128x128 tile, BK=32, staging via
// global_load_lds width=16 (the 517->874 TF step on the learn_hip ladder),
// 2-barrier K-loop, MFMA 16x16x32 bf16. Attention kernel unchanged.

typedef __bf16 bf16_t;
typedef __bf16 bf16x8 __attribute__((ext_vector_type(8)));
typedef float floatx4 __attribute__((ext_vector_type(4)));

#define MFMA16(a, b, c) __builtin_amdgcn_mfma_f32_16x16x32_bf16((a), (b), (c), 0, 0, 0)

__device__ __forceinline__ void gload_lds16(const bf16_t* g, bf16_t* l)
{
    __builtin_amdgcn_global_load_lds(
        (const __attribute__((address_space(1))) void*)g,
        (__attribute__((address_space(3))) void*)l, 16, 0, 0);
}

// ---------------------------------------------------------------------------
// fp32 -> bf16 converters (memory-bound; vectorized 8 elems/thread)
// ---------------------------------------------------------------------------
__global__ __launch_bounds__(256) void cvt_big(
    const float* __restrict__ in, bf16_t* __restrict__ out, long long n8)
{
    for (long long i = (long long)blockIdx.x * 256 + threadIdx.x; i < n8;
         i += (long long)gridDim.x * 256) {
        floatx4 f0 = *(const floatx4*)(in + i * 8);
        floatx4 f1 = *(const floatx4*)(in + i * 8 + 4);
        bf16x8 v;
#pragma unroll
        for (int e = 0; e < 4; e++) { v[e] = (bf16_t)f0[e]; v[e + 4] = (bf16_t)f1[e]; }
        *(bf16x8*)(out + i * 8) = v;
    }
}

struct Cvt5 {
    const float* s[5];
    bf16_t* d[5];
    int n8[5];
};

// grid: (maxBlocks, 5) — y selects the tensor, x covers it (guarded).
__global__ __launch_bounds__(256) void cvt_multi(Cvt5 c)
{
    const int seg = blockIdx.y;
    const long long i = (long long)blockIdx.x * 256 + threadIdx.x;
    if (i >= c.n8[seg]) return;
    const float* in = c.s[seg];
    bf16_t* out = c.d[seg];
    floatx4 f0 = *(const floatx4*)(in + i * 8);
    floatx4 f1 = *(const floatx4*)(in + i * 8 + 4);
    bf16x8 v;
#pragma unroll
    for (int e = 0; e < 4; e++) { v[e] = (bf16_t)f0[e]; v[e + 4] = (bf16_t)f1[e]; }
    *(bf16x8*)(out + i * 8) = v;
}

// ---------------------------------------------------------------------------
// C[M,N] = A[M,K] @ B[N,K]^T   (all bf16 in; CF32 selects output dtype)
// m97 structure: 128x128 tile, BK=32, global_load_lds width-16 staging,
// 4 waves (2x2), each computes 64x64 via 4x4 16x16x32 MFMA fragments.
// grid: (N/128, ceil(M/128)), block 256.
// ---------------------------------------------------------------------------
template <bool CF32>
__global__ __launch_bounds__(256) void gemm_bt(
    const bf16_t* __restrict__ A, const bf16_t* __restrict__ B,
    void* __restrict__ Cv, int M, int N, int K)
{
    __shared__ bf16_t As[128 * 32];   // linear [128][32] (gload_lds needs linear)
    __shared__ bf16_t Bs[128 * 32];

    const int t = threadIdx.x;
    const int l = t & 63;
    const int w = t >> 6;
    const int wm = w >> 1, wn = w & 1;          // 2x2 wave layout
    const int l15 = l & 15, l4 = l >> 4;
    const int m0 = blockIdx.y * 128, n0 = blockIdx.x * 128;

    floatx4 acc[4][4] = {};

    // staging geometry: 256 threads x 2 iters x 8 bf16 (16B) = full 128x32 tile.
    // LDS dest (i*256+t)*16 B = wave-uniform base + lane*16  (gload_lds rule).
    const bf16_t* ag[2];
    const bf16_t* bg[2];
    bf16_t* al[2];
    bf16_t* bl[2];
#pragma unroll
    for (int i = 0; i < 2; i++) {
        int e = (i * 256 + t) * 8;       // flat elem idx in [128][32]
        int row = e >> 5, col = e & 31;
        int ra = m0 + row; if (ra > M - 1) ra = M - 1;   // clamp (M=1232 case)
        ag[i] = A + (size_t)ra * K + col;
        bg[i] = B + (size_t)(n0 + row) * K + col;
        al[i] = &As[e];
        bl[i] = &Bs[e];
    }

    for (int k0 = 0; k0 < K; k0 += 32) {
#pragma unroll
        for (int i = 0; i < 2; i++) {
            gload_lds16(ag[i] + k0, al[i]);
            gload_lds16(bg[i] + k0, bl[i]);
        }
        __syncthreads();   // compiler emits vmcnt(0) drain before barrier

        bf16x8 af[4], bfr[4];
#pragma unroll
        for (int i = 0; i < 4; i++)
            af[i] = *(const bf16x8*)&As[(wm * 64 + i * 16 + l15) * 32 + l4 * 8];
#pragma unroll
        for (int j = 0; j < 4; j++)
            bfr[j] = *(const bf16x8*)&Bs[(wn * 64 + j * 16 + l15) * 32 + l4 * 8];
#pragma unroll
        for (int i = 0; i < 4; i++)
#pragma unroll
            for (int j = 0; j < 4; j++)
                acc[i][j] = MFMA16(af[i], bfr[j], acc[i][j]);
        __syncthreads();
    }

    // epilogue: C/D layout col=lane&15, row=(lane>>4)*4+reg
#pragma unroll
    for (int i = 0; i < 4; i++)
#pragma unroll
        for (int j = 0; j < 4; j++)
#pragma unroll
            for (int r = 0; r < 4; r++) {
                int row = m0 + wm * 64 + i * 16 + l4 * 4 + r;
                int col = n0 + wn * 64 + j * 16 + l15;
                if (row < M) {
                    if (CF32) ((float*)Cv)[(size_t)row * N + col] = acc[i][j][r];
                    else ((bf16_t*)Cv)[(size_t)row * N + col] = (bf16_t)acc[i][j][r];
                }
            }
}

// ---------------------------------------------------------------------------
// Fused attention, IN-PLACE on QO (bf16 workspace): reads Q slice into regs,
// writes O to the same slice. Disjoint across blocks.  (unchanged from R4)
// grid: (Lq/64, B*H), block 256; wave w handles q-rows q0+16w..+16.
// ---------------------------------------------------------------------------
#define LK 77
#define KSTR 72    // Ks row stride (2-way bank aliasing only — free)
#define VSTR 104   // Vt / Ps row stride
#define JP 96      // j padded to 3 MFMA k-steps

__global__ __launch_bounds__(256) void attn_fused(
    bf16_t* QO,                              // aliased read+write, no restrict
    const bf16_t* __restrict__ Kg,
    const bf16_t* __restrict__ Vg)
{
    __shared__ bf16_t Ks[80 * KSTR];        // K rows [j][d], rows 77..79 zeroed
    __shared__ bf16_t Vs[64 * VSTR];        // V^T [d][j], j>=77 zeroed
    __shared__ bf16_t Ps[4 * 16 * VSTR];    // per-wave P [16][96+pad]

    const int t = threadIdx.x;
    const int w = t >> 6, l = t & 63;
    const int l15 = l & 15, l4 = l >> 4;
    const int b = blockIdx.y >> 3, h = blockIdx.y & 7;
    const int q0 = blockIdx.x * 64;

    // --- stage K rows (vector 16B) ---
    for (int idx = t; idx < LK * 8; idx += 256) {
        int j = idx >> 3, c = (idx & 7) * 8;
        *(uint4*)&Ks[j * KSTR + c] =
            *(const uint4*)&Kg[((size_t)(b * LK + j)) * 512 + h * 64 + c];
    }
    for (int idx = t; idx < 3 * KSTR; idx += 256)   // zero pad rows 77..79
        Ks[LK * KSTR + idx] = (bf16_t)0.0f;

    // --- stage V transposed ---
    for (int idx = t; idx < LK * 64; idx += 256) {
        int j = idx >> 6, d = idx & 63;
        Vs[d * VSTR + j] = Vg[((size_t)(b * LK + j)) * 512 + h * 64 + d];
    }
    for (int idx = t; idx < 64 * (JP - LK); idx += 256) {
        int d = idx / (JP - LK), j = LK + idx % (JP - LK);
        Vs[d * VSTR + j] = (bf16_t)0.0f;
    }
    __syncthreads();

    // --- Q fragments from global (A-layout: m=lane&15, k=(lane>>4)*8) ---
    const bf16_t* qbase =
        QO + ((size_t)(b * 4096 + q0 + w * 16 + l15)) * 512 + h * 64 + l4 * 8;
    bf16x8 aq0 = *(const bf16x8*)qbase;
    bf16x8 aq1 = *(const bf16x8*)(qbase + 32);

    // --- S = Q K^T (5 col-tiles of 16, 2 k-steps) ---
    floatx4 s[5];
#pragma unroll
    for (int n = 0; n < 5; n++) {
        floatx4 z = {0.f, 0.f, 0.f, 0.f};
        bf16x8 b0 = *(const bf16x8*)&Ks[(n * 16 + l15) * KSTR + l4 * 8];
        bf16x8 b1 = *(const bf16x8*)&Ks[(n * 16 + l15) * KSTR + 32 + l4 * 8];
        z = MFMA16(aq0, b0, z);
        z = MFMA16(aq1, b1, z);
        s[n] = z;
    }

    // --- in-register softmax (row r lives across the 16 lanes sharing l>>4) ---
    const float scale = 0.125f;   // 64^-0.5
    float p[5][4], linv[4];
#pragma unroll
    for (int r = 0; r < 4; r++) {
        float smax = -1e30f;
#pragma unroll
        for (int n = 0; n < 5; n++) {
            float v = s[n][r] * scale;
            if (n == 4 && (64 + l15) >= LK) v = -1e30f;   // mask j>=77
            p[n][r] = v;
            smax = fmaxf(smax, v);
        }
#pragma unroll
        for (int off = 1; off < 16; off <<= 1)
            smax = fmaxf(smax, __shfl_xor(smax, off, 64));
        float sum = 0.f;
#pragma unroll
        for (int n = 0; n < 5; n++) {
            float e = __expf(p[n][r] - smax);
            p[n][r] = e;
            sum += e;
        }
#pragma unroll
        for (int off = 1; off < 16; off <<= 1)
            sum += __shfl_xor(sum, off, 64);
        linv[r] = 1.0f / sum;
    }

    // --- write normalized P to LDS (C-layout -> A-layout transform) ---
    bf16_t* pw = Ps + w * 16 * VSTR;
#pragma unroll
    for (int r = 0; r < 4; r++) {
        int row = l4 * 4 + r;
#pragma unroll
        for (int n = 0; n < 5; n++)
            pw[row * VSTR + n * 16 + l15] = (bf16_t)(p[n][r] * linv[r]);
        pw[row * VSTR + 80 + l15] = (bf16_t)0.0f;     // zero j=80..95
    }
    __syncthreads();

    // --- O = P V (4 d-tiles, 3 k-steps over padded j=96), in-place over Q ---
    bf16x8 ap[3];
#pragma unroll
    for (int ks = 0; ks < 3; ks++)
        ap[ks] = *(const bf16x8*)&pw[l15 * VSTR + ks * 32 + l4 * 8];
#pragma unroll
    for (int n2 = 0; n2 < 4; n2++) {
        floatx4 o = {0.f, 0.f, 0.f, 0.f};
#pragma unroll
        for (int ks = 0; ks < 3; ks++) {
            bf16x8 bv = *(const bf16x8*)&Vs[(n2 * 16 + l15) * VSTR + ks * 32 + l4 * 8];
            o = MFMA16(ap[ks], bv, o);
        }
#pragma unroll
        for (int r = 0; r < 4; r++) {
            int q = q0 + w * 16 + l4 * 4 + r;
            QO[((size_t)(b * 4096 + q)) * 512 + h * 64 + n2 * 16 + l15] = (bf16_t)o[r];
        }
    }
}

// ---------------------------------------------------------------------------
extern "C" void kernel_launch(void* const* d_in, const int* in_sizes, int n_in,
                              void* d_out, int out_size, void* d_ws, size_t ws_size,
                              hipStream_t stream)
{
    const float* x    = (const float*)d_in[0];  // [16,4096,512] fp32
    const float* cond = (const float*)d_in[1];  // [16,77,768]   fp32
    const float* w_q  = (const float*)d_in[2];  // [512,512]     fp32
    const float* w_k  = (const float*)d_in[3];  // [512,768]     fp32
    const float* w_v  = (const float*)d_in[4];  // [512,768]     fp32
    const float* w_o  = (const float*)d_in[5];  // [512,512]     fp32
    float* out = (float*)d_out;                 // [16,4096,512] fp32

    const int Mq  = 16 * 4096;   // 65536
    const int Mkv = 16 * 77;     // 1232

    // workspace (bf16): Q/AO 67.1MB | K 1.26MB | V 1.26MB | Wo 0.5MB  (~70.2 MB)
    bf16_t* Qb  = (bf16_t*)d_ws;
    bf16_t* Kb  = Qb + (size_t)Mq * 512;
    bf16_t* Vb  = Kb + (size_t)Mkv * 512;
    bf16_t* Wob = Vb + (size_t)Mkv * 512;

    // d_out doubles as scratch for bf16 inputs (dead until the final O-proj):
    // Xb 67.1MB | Cb 1.9MB | Wq 0.5 | Wk 0.75 | Wv 0.75  = 71.1MB <= 134.2MB
    bf16_t* Xb  = (bf16_t*)d_out;
    bf16_t* Cb  = Xb  + (size_t)Mq * 512;
    bf16_t* Wqb = Cb  + (size_t)Mkv * 768;
    bf16_t* Wkb = Wqb + (size_t)512 * 512;
    bf16_t* Wvb = Wkb + (size_t)512 * 768;

    // --- 1. fp32 -> bf16 conversion passes ---
    const long long n8x = (long long)Mq * 512 / 8;          // 4,194,304
    cvt_big<<<dim3(2048), 256, 0, stream>>>(x, Xb, n8x);

    Cvt5 c;
    c.s[0] = cond; c.d[0] = Cb;  c.n8[0] = Mkv * 768 / 8;   // 118,272
    c.s[1] = w_q;  c.d[1] = Wqb; c.n8[1] = 512 * 512 / 8;   //  32,768
    c.s[2] = w_k;  c.d[2] = Wkb; c.n8[2] = 512 * 768 / 8;   //  49,152
    c.s[3] = w_v;  c.d[3] = Wvb; c.n8[3] = 512 * 768 / 8;   //  49,152
    c.s[4] = w_o;  c.d[4] = Wob; c.n8[4] = 512 * 512 / 8;   //  32,768
    cvt_multi<<<dim3((118272 + 255) / 256, 5), 256, 0, stream>>>(c);

    // --- 2. projections (pure-bf16 m97 GEMM) ---
    gemm_bt<false><<<dim3(4, Mq / 128), 256, 0, stream>>>(Xb, Wqb, Qb, Mq, 512, 512);
    gemm_bt<false><<<dim3(4, (Mkv + 127) / 128), 256, 0, stream>>>(Cb, Wkb, Kb, Mkv, 512, 768);
    gemm_bt<false><<<dim3(4, (Mkv + 127) / 128), 256, 0, stream>>>(Cb, Wvb, Vb, Mkv, 512, 768);

    // --- 3. fused attention (Q -> AO in place) ---
    attn_fused<<<dim3(64, 128), 256, 0, stream>>>(Qb, Kb, Vb);

    // --- 4. O-projection (reads ws only; overwrites the d_out scratch) ---
    gemm_bt<true><<<dim3(4, Mq / 128), 256, 0, stream>>>(Qb, Wob, out, Mq, 512, 512);
}

// Round 2
// 445.151 us; speedup vs baseline: 1.0105x; 1.0105x over previous
//
#include <hip/hip_runtime.h>
#include <hip/hip_bf16.h>
#include <stdint.h>

// CrossAttnBlock: out = softmax((x Wq^T)(cond Wk^T)^T / 8) (cond Wv^T) Wo^T
// B=16 Lq=4096 Lk=77 D=512 Dc=768 H=8 Hd=64.
//
// R6 change (attention only; GEMMs/cvt unchanged as A/B control):
//  - attn QBLK 64->128: wave owns 32 q-rows (2 M-frags) -> half the blocks,
//    K/V staging + barriers amortized 2x.
//  - V staging vectorized: uint4 global reads (was 4928 scalar 2B loads/blk).
//  - Q fragment loads hoisted above staging (latency overlap).
//  - s_setprio(1) around MFMA clusters (T5, +4-7% attn per m191).

typedef __bf16 bf16_t;
typedef __bf16 bf16x8 __attribute__((ext_vector_type(8)));
typedef float floatx4 __attribute__((ext_vector_type(4)));

#define MFMA16(a, b, c) __builtin_amdgcn_mfma_f32_16x16x32_bf16((a), (b), (c), 0, 0, 0)

__device__ __forceinline__ void gload_lds16(const bf16_t* g, bf16_t* l)
{
    __builtin_amdgcn_global_load_lds(
        (const __attribute__((address_space(1))) void*)g,
        (__attribute__((address_space(3))) void*)l, 16, 0, 0);
}

// ---------------------------------------------------------------------------
// fp32 -> bf16 converters (memory-bound; vectorized 8 elems/thread)
// ---------------------------------------------------------------------------
__global__ __launch_bounds__(256) void cvt_big(
    const float* __restrict__ in, bf16_t* __restrict__ out, long long n8)
{
    for (long long i = (long long)blockIdx.x * 256 + threadIdx.x; i < n8;
         i += (long long)gridDim.x * 256) {
        floatx4 f0 = *(const floatx4*)(in + i * 8);
        floatx4 f1 = *(const floatx4*)(in + i * 8 + 4);
        bf16x8 v;
#pragma unroll
        for (int e = 0; e < 4; e++) { v[e] = (bf16_t)f0[e]; v[e + 4] = (bf16_t)f1[e]; }
        *(bf16x8*)(out + i * 8) = v;
    }
}

struct Cvt5 {
    const float* s[5];
    bf16_t* d[5];
    int n8[5];
};

__global__ __launch_bounds__(256) void cvt_multi(Cvt5 c)
{
    const int seg = blockIdx.y;
    const long long i = (long long)blockIdx.x * 256 + threadIdx.x;
    if (i >= c.n8[seg]) return;
    const float* in = c.s[seg];
    bf16_t* out = c.d[seg];
    floatx4 f0 = *(const floatx4*)(in + i * 8);
    floatx4 f1 = *(const floatx4*)(in + i * 8 + 4);
    bf16x8 v;
#pragma unroll
    for (int e = 0; e < 4; e++) { v[e] = (bf16_t)f0[e]; v[e + 4] = (bf16_t)f1[e]; }
    *(bf16x8*)(out + i * 8) = v;
}

// ---------------------------------------------------------------------------
// C[M,N] = A[M,K] @ B[N,K]^T   (bf16 in; CF32 selects output dtype)
// m97 structure: 128x128 tile, BK=32, global_load_lds width-16 staging.
// UNCHANGED from R5 (control for this round's A/B).
// ---------------------------------------------------------------------------
template <bool CF32>
__global__ __launch_bounds__(256) void gemm_bt(
    const bf16_t* __restrict__ A, const bf16_t* __restrict__ B,
    void* __restrict__ Cv, int M, int N, int K)
{
    __shared__ bf16_t As[128 * 32];
    __shared__ bf16_t Bs[128 * 32];

    const int t = threadIdx.x;
    const int l = t & 63;
    const int w = t >> 6;
    const int wm = w >> 1, wn = w & 1;
    const int l15 = l & 15, l4 = l >> 4;
    const int m0 = blockIdx.y * 128, n0 = blockIdx.x * 128;

    floatx4 acc[4][4] = {};

    const bf16_t* ag[2];
    const bf16_t* bg[2];
    bf16_t* al[2];
    bf16_t* bl[2];
#pragma unroll
    for (int i = 0; i < 2; i++) {
        int e = (i * 256 + t) * 8;
        int row = e >> 5, col = e & 31;
        int ra = m0 + row; if (ra > M - 1) ra = M - 1;
        ag[i] = A + (size_t)ra * K + col;
        bg[i] = B + (size_t)(n0 + row) * K + col;
        al[i] = &As[e];
        bl[i] = &Bs[e];
    }

    for (int k0 = 0; k0 < K; k0 += 32) {
#pragma unroll
        for (int i = 0; i < 2; i++) {
            gload_lds16(ag[i] + k0, al[i]);
            gload_lds16(bg[i] + k0, bl[i]);
        }
        __syncthreads();

        bf16x8 af[4], bfr[4];
#pragma unroll
        for (int i = 0; i < 4; i++)
            af[i] = *(const bf16x8*)&As[(wm * 64 + i * 16 + l15) * 32 + l4 * 8];
#pragma unroll
        for (int j = 0; j < 4; j++)
            bfr[j] = *(const bf16x8*)&Bs[(wn * 64 + j * 16 + l15) * 32 + l4 * 8];
#pragma unroll
        for (int i = 0; i < 4; i++)
#pragma unroll
            for (int j = 0; j < 4; j++)
                acc[i][j] = MFMA16(af[i], bfr[j], acc[i][j]);
        __syncthreads();
    }

#pragma unroll
    for (int i = 0; i < 4; i++)
#pragma unroll
        for (int j = 0; j < 4; j++)
#pragma unroll
            for (int r = 0; r < 4; r++) {
                int row = m0 + wm * 64 + i * 16 + l4 * 4 + r;
                int col = n0 + wn * 64 + j * 16 + l15;
                if (row < M) {
                    if (CF32) ((float*)Cv)[(size_t)row * N + col] = acc[i][j][r];
                    else ((bf16_t*)Cv)[(size_t)row * N + col] = (bf16_t)acc[i][j][r];
                }
            }
}

// ---------------------------------------------------------------------------
// Fused attention, IN-PLACE on QO. R6: 128 q-rows/block, 32 rows/wave.
// grid: (Lq/128, B*H), block 256.
// ---------------------------------------------------------------------------
#define LK 77
#define KSTR 72    // Ks row stride (2-way bank aliasing only — free)
#define VSTR 104   // Vt / Ps row stride (2-way only)
#define JP 96      // j padded to 3 MFMA k-steps

__global__ __launch_bounds__(256) void attn_fused(
    bf16_t* QO,                              // aliased read+write, no restrict
    const bf16_t* __restrict__ Kg,
    const bf16_t* __restrict__ Vg)
{
    __shared__ bf16_t Ks[80 * KSTR];        // K rows [j][d], rows 77..79 zeroed
    __shared__ bf16_t Vs[64 * VSTR];        // V^T [d][j], j>=77 zeroed
    __shared__ bf16_t Ps[4 * 32 * VSTR];    // per-wave P [32][96+pad]

    const int t = threadIdx.x;
    const int w = t >> 6, l = t & 63;
    const int l15 = l & 15, l4 = l >> 4;
    const int b = blockIdx.y >> 3, h = blockIdx.y & 7;
    const int q0 = blockIdx.x * 128;

    // --- Q fragments issued FIRST (global latency hides under staging) ---
    // A-layout: m=lane&15, k=(lane>>4)*8; wave rows w*32 + mi*16 + l15.
    const bf16_t* qbase =
        QO + ((size_t)(b * 4096 + q0 + w * 32 + l15)) * 512 + h * 64 + l4 * 8;
    bf16x8 aq[2][2];
    aq[0][0] = *(const bf16x8*)qbase;
    aq[0][1] = *(const bf16x8*)(qbase + 32);
    aq[1][0] = *(const bf16x8*)(qbase + 16 * 512);
    aq[1][1] = *(const bf16x8*)(qbase + 16 * 512 + 32);

    // --- stage K rows (vector 16B) ---
    for (int idx = t; idx < LK * 8; idx += 256) {
        int j = idx >> 3, c = (idx & 7) * 8;
        *(uint4*)&Ks[j * KSTR + c] =
            *(const uint4*)&Kg[((size_t)(b * LK + j)) * 512 + h * 64 + c];
    }
    for (int idx = t; idx < 3 * KSTR; idx += 256)   // zero pad rows 77..79
        Ks[LK * KSTR + idx] = (bf16_t)0.0f;

    // --- stage V transposed: uint4 global read + scalar LDS scatter ---
    for (int u = t; u < LK * 8; u += 256) {
        int j = u >> 3, d0 = (u & 7) * 8;
        uint4 pk = *(const uint4*)&Vg[((size_t)(b * LK + j)) * 512 + h * 64 + d0];
        const bf16_t* pv = (const bf16_t*)&pk;
#pragma unroll
        for (int e = 0; e < 8; e++)
            Vs[(d0 + e) * VSTR + j] = pv[e];
    }
    for (int idx = t; idx < 64 * (JP - LK); idx += 256) {
        int d = idx / (JP - LK), j = LK + idx % (JP - LK);
        Vs[d * VSTR + j] = (bf16_t)0.0f;
    }
    __syncthreads();

    // --- S = Q K^T : 2 row-frags x 5 col-tiles x 2 k-steps ---
    floatx4 s[2][5];
    __builtin_amdgcn_s_setprio(1);
#pragma unroll
    for (int n = 0; n < 5; n++) {
        bf16x8 b0 = *(const bf16x8*)&Ks[(n * 16 + l15) * KSTR + l4 * 8];
        bf16x8 b1 = *(const bf16x8*)&Ks[(n * 16 + l15) * KSTR + 32 + l4 * 8];
#pragma unroll
        for (int mi = 0; mi < 2; mi++) {
            floatx4 z = {0.f, 0.f, 0.f, 0.f};
            z = MFMA16(aq[mi][0], b0, z);
            z = MFMA16(aq[mi][1], b1, z);
            s[mi][n] = z;
        }
    }
    __builtin_amdgcn_s_setprio(0);

    // --- in-register softmax (row lives across the 16 lanes sharing l4) ---
    const float scale = 0.125f;
    float p[2][5][4], linv[2][4];
#pragma unroll
    for (int mi = 0; mi < 2; mi++)
#pragma unroll
        for (int r = 0; r < 4; r++) {
            float smax = -1e30f;
#pragma unroll
            for (int n = 0; n < 5; n++) {
                float v = s[mi][n][r] * scale;
                if (n == 4 && (64 + l15) >= LK) v = -1e30f;   // mask j>=77
                p[mi][n][r] = v;
                smax = fmaxf(smax, v);
            }
#pragma unroll
            for (int off = 1; off < 16; off <<= 1)
                smax = fmaxf(smax, __shfl_xor(smax, off, 64));
            float sum = 0.f;
#pragma unroll
            for (int n = 0; n < 5; n++) {
                float e2 = __expf(p[mi][n][r] - smax);
                p[mi][n][r] = e2;
                sum += e2;
            }
#pragma unroll
            for (int off = 1; off < 16; off <<= 1)
                sum += __shfl_xor(sum, off, 64);
            linv[mi][r] = 1.0f / sum;
        }

    // --- write normalized P to LDS (C-layout -> A-layout transform) ---
    bf16_t* pw = Ps + w * 32 * VSTR;
#pragma unroll
    for (int mi = 0; mi < 2; mi++)
#pragma unroll
        for (int r = 0; r < 4; r++) {
            int row = mi * 16 + l4 * 4 + r;
#pragma unroll
            for (int n = 0; n < 5; n++)
                pw[row * VSTR + n * 16 + l15] = (bf16_t)(p[mi][n][r] * linv[mi][r]);
            pw[row * VSTR + 80 + l15] = (bf16_t)0.0f;     // zero j=80..95
        }
    __syncthreads();

    // --- O = P V (4 d-tiles, 3 k-steps over padded j=96), in-place over Q ---
    bf16x8 ap[2][3];
#pragma unroll
    for (int mi = 0; mi < 2; mi++)
#pragma unroll
        for (int ks = 0; ks < 3; ks++)
            ap[mi][ks] = *(const bf16x8*)&pw[(mi * 16 + l15) * VSTR + ks * 32 + l4 * 8];
#pragma unroll
    for (int n2 = 0; n2 < 4; n2++) {
        bf16x8 bv[3];
#pragma unroll
        for (int ks = 0; ks < 3; ks++)
            bv[ks] = *(const bf16x8*)&Vs[(n2 * 16 + l15) * VSTR + ks * 32 + l4 * 8];
        floatx4 o[2];
        __builtin_amdgcn_s_setprio(1);
#pragma unroll
        for (int mi = 0; mi < 2; mi++) {
            floatx4 z = {0.f, 0.f, 0.f, 0.f};
#pragma unroll
            for (int ks = 0; ks < 3; ks++)
                z = MFMA16(ap[mi][ks], bv[ks], z);
            o[mi] = z;
        }
        __builtin_amdgcn_s_setprio(0);
#pragma unroll
        for (int mi = 0; mi < 2; mi++)
#pragma unroll
            for (int r = 0; r < 4; r++) {
                int q = q0 + w * 32 + mi * 16 + l4 * 4 + r;
                QO[((size_t)(b * 4096 + q)) * 512 + h * 64 + n2 * 16 + l15] =
                    (bf16_t)o[mi][r];
            }
    }
}

// ---------------------------------------------------------------------------
extern "C" void kernel_launch(void* const* d_in, const int* in_sizes, int n_in,
                              void* d_out, int out_size, void* d_ws, size_t ws_size,
                              hipStream_t stream)
{
    const float* x    = (const float*)d_in[0];  // [16,4096,512] fp32
    const float* cond = (const float*)d_in[1];  // [16,77,768]   fp32
    const float* w_q  = (const float*)d_in[2];  // [512,512]     fp32
    const float* w_k  = (const float*)d_in[3];  // [512,768]     fp32
    const float* w_v  = (const float*)d_in[4];  // [512,768]     fp32
    const float* w_o  = (const float*)d_in[5];  // [512,512]     fp32
    float* out = (float*)d_out;                 // [16,4096,512] fp32

    const int Mq  = 16 * 4096;   // 65536
    const int Mkv = 16 * 77;     // 1232

    // workspace (bf16): Q/AO 67.1MB | K 1.26MB | V 1.26MB | Wo 0.5MB
    bf16_t* Qb  = (bf16_t*)d_ws;
    bf16_t* Kb  = Qb + (size_t)Mq * 512;
    bf16_t* Vb  = Kb + (size_t)Mkv * 512;
    bf16_t* Wob = Vb + (size_t)Mkv * 512;

    // d_out doubles as scratch for bf16 inputs (dead until the final O-proj)
    bf16_t* Xb  = (bf16_t*)d_out;
    bf16_t* Cb  = Xb  + (size_t)Mq * 512;
    bf16_t* Wqb = Cb  + (size_t)Mkv * 768;
    bf16_t* Wkb = Wqb + (size_t)512 * 512;
    bf16_t* Wvb = Wkb + (size_t)512 * 768;

    // --- 1. fp32 -> bf16 conversion passes ---
    const long long n8x = (long long)Mq * 512 / 8;
    cvt_big<<<dim3(2048), 256, 0, stream>>>(x, Xb, n8x);

    Cvt5 c;
    c.s[0] = cond; c.d[0] = Cb;  c.n8[0] = Mkv * 768 / 8;
    c.s[1] = w_q;  c.d[1] = Wqb; c.n8[1] = 512 * 512 / 8;
    c.s[2] = w_k;  c.d[2] = Wkb; c.n8[2] = 512 * 768 / 8;
    c.s[3] = w_v;  c.d[3] = Wvb; c.n8[3] = 512 * 768 / 8;
    c.s[4] = w_o;  c.d[4] = Wob; c.n8[4] = 512 * 512 / 8;
    cvt_multi<<<dim3((118272 + 255) / 256, 5), 256, 0, stream>>>(c);

    // --- 2. projections (m97 GEMM, unchanged) ---
    gemm_bt<false><<<dim3(4, Mq / 128), 256, 0, stream>>>(Xb, Wqb, Qb, Mq, 512, 512);
    gemm_bt<false><<<dim3(4, (Mkv + 127) / 128), 256, 0, stream>>>(Cb, Wkb, Kb, Mkv, 512, 768);
    gemm_bt<false><<<dim3(4, (Mkv + 127) / 128), 256, 0, stream>>>(Cb, Wvb, Vb, Mkv, 512, 768);

    // --- 3. fused attention (Q -> AO in place), 128 q-rows/block ---
    attn_fused<<<dim3(32, 128), 256, 0, stream>>>(Qb, Kb, Vb);

    // --- 4. O-projection ---
    gemm_bt<true><<<dim3(4, Mq / 128), 256, 0, stream>>>(Qb, Wob, out, Mq, 512, 512);
}

// Round 3
// 403.260 us; speedup vs baseline: 1.1155x; 1.1039x over previous
//
#include <hip/hip_runtime.h>
#include <hip/hip_bf16.h>
#include <stdint.h>

// CrossAttnBlock: out = softmax((x Wq^T)(cond Wk^T)^T / 8) (cond Wv^T) Wo^T
// B=16 Lq=4096 Lk=77 D=512 Dc=768 H=8 Hd=64.
//
// R7 changes (attn unchanged as control):
//  - gemm_bt BK 32->64 with [2][128][32] split LDS subtiles (same per-phase
//    ds_read geometry as proven m97 structure; half the barriers/drains).
//  - XCD-chunked blockIdx swizzle (T1) on all GEMMs (bijective, nwg%8==0).
//  - K-proj and V-proj merged into one GEMM (N=1024, contiguous Wk|Wv weight;
//    KV interleaved row-stride-1024; attn reads with stride 1024).
//  - cvt_big + cvt_multi merged into one launch. 7 -> 5 dispatches.

typedef __bf16 bf16_t;
typedef __bf16 bf16x8 __attribute__((ext_vector_type(8)));
typedef float floatx4 __attribute__((ext_vector_type(4)));

#define MFMA16(a, b, c) __builtin_amdgcn_mfma_f32_16x16x32_bf16((a), (b), (c), 0, 0, 0)

__device__ __forceinline__ void gload_lds16(const bf16_t* g, bf16_t* l)
{
    __builtin_amdgcn_global_load_lds(
        (const __attribute__((address_space(1))) void*)g,
        (__attribute__((address_space(3))) void*)l, 16, 0, 0);
}

// ---------------------------------------------------------------------------
// fp32 -> bf16 conversion, single launch.
// grid (2048, 2): y=0 grid-strides the big x tensor; y=1 covers the 5 small
// tensors via static block-range partition (sizes are compile-time-known).
// ---------------------------------------------------------------------------
struct CvtArgs {
    const float* s[5];
    bf16_t* d[5];
};

__device__ __forceinline__ void cvt8(const float* in, bf16_t* out, long long i)
{
    floatx4 f0 = *(const floatx4*)(in + i * 8);
    floatx4 f1 = *(const floatx4*)(in + i * 8 + 4);
    bf16x8 v;
#pragma unroll
    for (int e = 0; e < 4; e++) { v[e] = (bf16_t)f0[e]; v[e + 4] = (bf16_t)f1[e]; }
    *(bf16x8*)(out + i * 8) = v;
}

__global__ __launch_bounds__(256) void cvt_all(
    const float* __restrict__ x, bf16_t* __restrict__ xb, long long n8x, CvtArgs c)
{
    if (blockIdx.y == 0) {
        for (long long i = (long long)blockIdx.x * 256 + threadIdx.x; i < n8x;
             i += (long long)2048 * 256)
            cvt8(x, xb, i);
    } else {
        // block counts: cond 462 | wq 128 | wk 192 | wv 192 | wo 128 (exact)
        int gid = blockIdx.x, seg, base;
        if      (gid <  462) { seg = 0; base = 0;   }
        else if (gid <  590) { seg = 1; base = 462; }
        else if (gid <  782) { seg = 2; base = 590; }
        else if (gid <  974) { seg = 3; base = 782; }
        else if (gid < 1102) { seg = 4; base = 974; }
        else return;
        long long i = (long long)(gid - base) * 256 + threadIdx.x;
        cvt8(c.s[seg], c.d[seg], i);
    }
}

// ---------------------------------------------------------------------------
// C[M,N] = A[M,K] @ B[N,K]^T   (bf16 in; CF32 selects output dtype)
// 128x128 tile, BK=64 as two [128][32] subtiles (m97 ds_read geometry),
// global_load_lds width-16 staging, XCD-chunked swizzle.
// grid: (N/128, ceil(M/128)), block 256 (4 waves, 2x2).
// ---------------------------------------------------------------------------
template <bool CF32>
__global__ __launch_bounds__(256) void gemm_bt(
    const bf16_t* __restrict__ A, const bf16_t* __restrict__ B,
    void* __restrict__ Cv, int M, int N, int K)
{
    __shared__ bf16_t As[2 * 128 * 32];   // [kk][row][col0..31], 16 KB
    __shared__ bf16_t Bs[2 * 128 * 32];

    const int t = threadIdx.x;
    const int l = t & 63;
    const int w = t >> 6;
    const int wm = w >> 1, wn = w & 1;
    const int l15 = l & 15, l4 = l >> 4;

    // XCD-chunked swizzle (bijective; all our launches have nwg%8==0)
    const int nbx = gridDim.x;
    const int nwg = nbx * gridDim.y;
    int lid = blockIdx.y * nbx + blockIdx.x;
    if ((nwg & 7) == 0) {
        const int cpx = nwg >> 3;
        lid = (lid & 7) * cpx + (lid >> 3);
    }
    const int m0 = (lid / nbx) * 128, n0 = (lid % nbx) * 128;

    floatx4 acc[4][4] = {};

    // staging: 256 threads x 4 chunks x 16B = 16 KB = full [2][128][32] tile.
    // chunk flat-idx e maps to (kk = e>>12, row = (e&4095)>>5, col = kk*32+(e&31)).
    const bf16_t* ag[4];
    const bf16_t* bg[4];
    bf16_t* al[4];
    bf16_t* bl[4];
#pragma unroll
    for (int i = 0; i < 4; i++) {
        int e = (i * 256 + t) * 8;
        int kk = e >> 12;
        int row = (e & 4095) >> 5;
        int col = kk * 32 + (e & 31);
        int ra = m0 + row; if (ra > M - 1) ra = M - 1;   // clamp (M=1232 case)
        ag[i] = A + (size_t)ra * K + col;
        bg[i] = B + (size_t)(n0 + row) * K + col;
        al[i] = &As[e];
        bl[i] = &Bs[e];
    }

    for (int k0 = 0; k0 < K; k0 += 64) {
#pragma unroll
        for (int i = 0; i < 4; i++) {
            gload_lds16(ag[i] + k0, al[i]);
            gload_lds16(bg[i] + k0, bl[i]);
        }
        __syncthreads();

#pragma unroll
        for (int kk = 0; kk < 2; kk++) {
            bf16x8 af[4], bfr[4];
#pragma unroll
            for (int i = 0; i < 4; i++)
                af[i] = *(const bf16x8*)&As[kk * 4096 + (wm * 64 + i * 16 + l15) * 32 + l4 * 8];
#pragma unroll
            for (int j = 0; j < 4; j++)
                bfr[j] = *(const bf16x8*)&Bs[kk * 4096 + (wn * 64 + j * 16 + l15) * 32 + l4 * 8];
#pragma unroll
            for (int i = 0; i < 4; i++)
#pragma unroll
                for (int j = 0; j < 4; j++)
                    acc[i][j] = MFMA16(af[i], bfr[j], acc[i][j]);
        }
        __syncthreads();
    }

    // epilogue: C/D layout col=lane&15, row=(lane>>4)*4+reg
#pragma unroll
    for (int i = 0; i < 4; i++)
#pragma unroll
        for (int j = 0; j < 4; j++)
#pragma unroll
            for (int r = 0; r < 4; r++) {
                int row = m0 + wm * 64 + i * 16 + l4 * 4 + r;
                int col = n0 + wn * 64 + j * 16 + l15;
                if (row < M) {
                    if (CF32) ((float*)Cv)[(size_t)row * N + col] = acc[i][j][r];
                    else ((bf16_t*)Cv)[(size_t)row * N + col] = (bf16_t)acc[i][j][r];
                }
            }
}

// ---------------------------------------------------------------------------
// Fused attention, IN-PLACE on QO. 128 q-rows/block, 32 rows/wave.
// K/V live interleaved in one buffer: row j = [K(512) | V(512)], stride 1024.
// grid: (Lq/128, B*H), block 256.  (unchanged from R6 except KV strides)
// ---------------------------------------------------------------------------
#define LK 77
#define KVSTR 1024 // global row stride of interleaved KV
#define KSTR 72    // Ks row stride (2-way bank aliasing only — free)
#define VSTR 104   // Vt / Ps row stride (2-way only)
#define JP 96      // j padded to 3 MFMA k-steps

__global__ __launch_bounds__(256) void attn_fused(
    bf16_t* QO,                              // aliased read+write, no restrict
    const bf16_t* __restrict__ KVg)          // [Mkv][1024] = [K|V]
{
    __shared__ bf16_t Ks[80 * KSTR];        // K rows [j][d], rows 77..79 zeroed
    __shared__ bf16_t Vs[64 * VSTR];        // V^T [d][j], j>=77 zeroed
    __shared__ bf16_t Ps[4 * 32 * VSTR];    // per-wave P [32][96+pad]

    const int t = threadIdx.x;
    const int w = t >> 6, l = t & 63;
    const int l15 = l & 15, l4 = l >> 4;
    const int b = blockIdx.y >> 3, h = blockIdx.y & 7;
    const int q0 = blockIdx.x * 128;

    // --- Q fragments issued FIRST (global latency hides under staging) ---
    const bf16_t* qbase =
        QO + ((size_t)(b * 4096 + q0 + w * 32 + l15)) * 512 + h * 64 + l4 * 8;
    bf16x8 aq[2][2];
    aq[0][0] = *(const bf16x8*)qbase;
    aq[0][1] = *(const bf16x8*)(qbase + 32);
    aq[1][0] = *(const bf16x8*)(qbase + 16 * 512);
    aq[1][1] = *(const bf16x8*)(qbase + 16 * 512 + 32);

    const bf16_t* Kg = KVg;                  // col 0..511 of each row
    const bf16_t* Vg = KVg + 512;            // col 512..1023

    // --- stage K rows (vector 16B) ---
    for (int idx = t; idx < LK * 8; idx += 256) {
        int j = idx >> 3, c = (idx & 7) * 8;
        *(uint4*)&Ks[j * KSTR + c] =
            *(const uint4*)&Kg[((size_t)(b * LK + j)) * KVSTR + h * 64 + c];
    }
    for (int idx = t; idx < 3 * KSTR; idx += 256)   // zero pad rows 77..79
        Ks[LK * KSTR + idx] = (bf16_t)0.0f;

    // --- stage V transposed: uint4 global read + scalar LDS scatter ---
    for (int u = t; u < LK * 8; u += 256) {
        int j = u >> 3, d0 = (u & 7) * 8;
        uint4 pk = *(const uint4*)&Vg[((size_t)(b * LK + j)) * KVSTR + h * 64 + d0];
        const bf16_t* pv = (const bf16_t*)&pk;
#pragma unroll
        for (int e = 0; e < 8; e++)
            Vs[(d0 + e) * VSTR + j] = pv[e];
    }
    for (int idx = t; idx < 64 * (JP - LK); idx += 256) {
        int d = idx / (JP - LK), j = LK + idx % (JP - LK);
        Vs[d * VSTR + j] = (bf16_t)0.0f;
    }
    __syncthreads();

    // --- S = Q K^T : 2 row-frags x 5 col-tiles x 2 k-steps ---
    floatx4 s[2][5];
    __builtin_amdgcn_s_setprio(1);
#pragma unroll
    for (int n = 0; n < 5; n++) {
        bf16x8 b0 = *(const bf16x8*)&Ks[(n * 16 + l15) * KSTR + l4 * 8];
        bf16x8 b1 = *(const bf16x8*)&Ks[(n * 16 + l15) * KSTR + 32 + l4 * 8];
#pragma unroll
        for (int mi = 0; mi < 2; mi++) {
            floatx4 z = {0.f, 0.f, 0.f, 0.f};
            z = MFMA16(aq[mi][0], b0, z);
            z = MFMA16(aq[mi][1], b1, z);
            s[mi][n] = z;
        }
    }
    __builtin_amdgcn_s_setprio(0);

    // --- in-register softmax (row lives across the 16 lanes sharing l4) ---
    const float scale = 0.125f;
    float p[2][5][4], linv[2][4];
#pragma unroll
    for (int mi = 0; mi < 2; mi++)
#pragma unroll
        for (int r = 0; r < 4; r++) {
            float smax = -1e30f;
#pragma unroll
            for (int n = 0; n < 5; n++) {
                float v = s[mi][n][r] * scale;
                if (n == 4 && (64 + l15) >= LK) v = -1e30f;   // mask j>=77
                p[mi][n][r] = v;
                smax = fmaxf(smax, v);
            }
#pragma unroll
            for (int off = 1; off < 16; off <<= 1)
                smax = fmaxf(smax, __shfl_xor(smax, off, 64));
            float sum = 0.f;
#pragma unroll
            for (int n = 0; n < 5; n++) {
                float e2 = __expf(p[mi][n][r] - smax);
                p[mi][n][r] = e2;
                sum += e2;
            }
#pragma unroll
            for (int off = 1; off < 16; off <<= 1)
                sum += __shfl_xor(sum, off, 64);
            linv[mi][r] = 1.0f / sum;
        }

    // --- write normalized P to LDS (C-layout -> A-layout transform) ---
    bf16_t* pw = Ps + w * 32 * VSTR;
#pragma unroll
    for (int mi = 0; mi < 2; mi++)
#pragma unroll
        for (int r = 0; r < 4; r++) {
            int row = mi * 16 + l4 * 4 + r;
#pragma unroll
            for (int n = 0; n < 5; n++)
                pw[row * VSTR + n * 16 + l15] = (bf16_t)(p[mi][n][r] * linv[mi][r]);
            pw[row * VSTR + 80 + l15] = (bf16_t)0.0f;     // zero j=80..95
        }
    __syncthreads();

    // --- O = P V (4 d-tiles, 3 k-steps over padded j=96), in-place over Q ---
    bf16x8 ap[2][3];
#pragma unroll
    for (int mi = 0; mi < 2; mi++)
#pragma unroll
        for (int ks = 0; ks < 3; ks++)
            ap[mi][ks] = *(const bf16x8*)&pw[(mi * 16 + l15) * VSTR + ks * 32 + l4 * 8];
#pragma unroll
    for (int n2 = 0; n2 < 4; n2++) {
        bf16x8 bv[3];
#pragma unroll
        for (int ks = 0; ks < 3; ks++)
            bv[ks] = *(const bf16x8*)&Vs[(n2 * 16 + l15) * VSTR + ks * 32 + l4 * 8];
        floatx4 o[2];
        __builtin_amdgcn_s_setprio(1);
#pragma unroll
        for (int mi = 0; mi < 2; mi++) {
            floatx4 z = {0.f, 0.f, 0.f, 0.f};
#pragma unroll
            for (int ks = 0; ks < 3; ks++)
                z = MFMA16(ap[mi][ks], bv[ks], z);
            o[mi] = z;
        }
        __builtin_amdgcn_s_setprio(0);
#pragma unroll
        for (int mi = 0; mi < 2; mi++)
#pragma unroll
            for (int r = 0; r < 4; r++) {
                int q = q0 + w * 32 + mi * 16 + l4 * 4 + r;
                QO[((size_t)(b * 4096 + q)) * 512 + h * 64 + n2 * 16 + l15] =
                    (bf16_t)o[mi][r];
            }
    }
}

// ---------------------------------------------------------------------------
extern "C" void kernel_launch(void* const* d_in, const int* in_sizes, int n_in,
                              void* d_out, int out_size, void* d_ws, size_t ws_size,
                              hipStream_t stream)
{
    const float* x    = (const float*)d_in[0];  // [16,4096,512] fp32
    const float* cond = (const float*)d_in[1];  // [16,77,768]   fp32
    const float* w_q  = (const float*)d_in[2];  // [512,512]     fp32
    const float* w_k  = (const float*)d_in[3];  // [512,768]     fp32
    const float* w_v  = (const float*)d_in[4];  // [512,768]     fp32
    const float* w_o  = (const float*)d_in[5];  // [512,512]     fp32
    float* out = (float*)d_out;                 // [16,4096,512] fp32

    const int Mq  = 16 * 4096;   // 65536
    const int Mkv = 16 * 77;     // 1232

    // workspace (bf16): Q/AO 67.1MB | KV interleaved 2.5MB | Wo 0.5MB
    bf16_t* Qb  = (bf16_t*)d_ws;
    bf16_t* KVb = Qb + (size_t)Mq * 512;
    bf16_t* Wob = KVb + (size_t)Mkv * 1024;

    // d_out doubles as scratch for bf16 inputs (dead until the final O-proj):
    // Xb 67.1 | Cb 1.9 | Wq 0.5 | Wkv 1.5  = 71 MB <= 124 MB
    bf16_t* Xb   = (bf16_t*)d_out;
    bf16_t* Cb   = Xb  + (size_t)Mq * 512;
    bf16_t* Wqb  = Cb  + (size_t)Mkv * 768;
    bf16_t* Wkvb = Wqb + (size_t)512 * 512;      // [1024][768]: Wk rows then Wv rows

    // --- 1. fp32 -> bf16 (single launch) ---
    CvtArgs c;
    c.s[0] = cond; c.d[0] = Cb;
    c.s[1] = w_q;  c.d[1] = Wqb;
    c.s[2] = w_k;  c.d[2] = Wkvb;                 // rows 0..511
    c.s[3] = w_v;  c.d[3] = Wkvb + (size_t)512 * 768;  // rows 512..1023
    c.s[4] = w_o;  c.d[4] = Wob;
    cvt_all<<<dim3(2048, 2), 256, 0, stream>>>(x, Xb, (long long)Mq * 512 / 8, c);

    // --- 2. projections ---
    gemm_bt<false><<<dim3(4, Mq / 128), 256, 0, stream>>>(Xb, Wqb, Qb, Mq, 512, 512);
    gemm_bt<false><<<dim3(8, (Mkv + 127) / 128), 256, 0, stream>>>(Cb, Wkvb, KVb, Mkv, 1024, 768);

    // --- 3. fused attention (Q -> AO in place) ---
    attn_fused<<<dim3(32, 128), 256, 0, stream>>>(Qb, KVb);

    // --- 4. O-projection ---
    gemm_bt<true><<<dim3(4, Mq / 128), 256, 0, stream>>>(Qb, Wob, out, Mq, 512, 512);
}

// Round 5
// 398.575 us; speedup vs baseline: 1.1286x; 1.0118x over previous
//
#include <hip/hip_runtime.h>
#include <hip/hip_bf16.h>
#include <stdint.h>

// CrossAttnBlock: out = softmax((x Wq^T)(cond Wk^T)^T / 8) (cond Wv^T) Wo^T
// B=16 Lq=4096 Lk=77 D=512 Dc=768 H=8 Hd=64.
//
// R9 = R8 resubmit (round-4 failure was container acquisition, not kernel):
//  - Q-proj reads x fp32 directly: A-side reg-staged with inline cvt,
//    B-side stays global_load_lds (weights L2-resident). Kills the Xb
//    bf16 round-trip (-134 MB HBM) and the big cvt pass.
//  - prep kernel: KV-proj from fp32 cond/wk/wv (both sides reg-staged cvt)
//    + wq/wo bf16 conversion, one launch. 4 dispatches total.
//  - attn, O-proj unchanged (controls). d_out no longer used as scratch.

typedef __bf16 bf16_t;
typedef __bf16 bf16x8 __attribute__((ext_vector_type(8)));
typedef float floatx4 __attribute__((ext_vector_type(4)));

#define MFMA16(a, b, c) __builtin_amdgcn_mfma_f32_16x16x32_bf16((a), (b), (c), 0, 0, 0)

__device__ __forceinline__ void gload_lds16(const bf16_t* g, bf16_t* l)
{
    __builtin_amdgcn_global_load_lds(
        (const __attribute__((address_space(1))) void*)g,
        (__attribute__((address_space(3))) void*)l, 16, 0, 0);
}

// load 8 fp32, convert, store bf16x8 (register-staged LDS write)
__device__ __forceinline__ void stage_cvt8(const float* g, bf16_t* l)
{
    floatx4 f0 = *(const floatx4*)g;
    floatx4 f1 = *(const floatx4*)(g + 4);
    bf16x8 v;
#pragma unroll
    for (int e = 0; e < 4; e++) { v[e] = (bf16_t)f0[e]; v[e + 4] = (bf16_t)f1[e]; }
    *(bf16x8*)l = v;
}

__device__ __forceinline__ void cvt8(const float* in, bf16_t* out, long long i)
{
    floatx4 f0 = *(const floatx4*)(in + i * 8);
    floatx4 f1 = *(const floatx4*)(in + i * 8 + 4);
    bf16x8 v;
#pragma unroll
    for (int e = 0; e < 4; e++) { v[e] = (bf16_t)f0[e]; v[e + 4] = (bf16_t)f1[e]; }
    *(bf16x8*)(out + i * 8) = v;
}

// ---------------------------------------------------------------------------
// C[M,N] = A[M,K] @ B[N,K]^T
// AF32: A is fp32, reg-staged with inline cvt; else bf16 via global_load_lds.
// B always bf16 via global_load_lds. CF32 selects output dtype.
// 128x128 tile, BK=64 as two [128][32] subtiles, XCD-chunked swizzle.
// grid: (N/128, M/128), block 256 (4 waves, 2x2).
// ---------------------------------------------------------------------------
template <bool AF32, bool CF32>
__global__ __launch_bounds__(256) void gemm_bt(
    const void* __restrict__ Av, const bf16_t* __restrict__ B,
    void* __restrict__ Cv, int M, int N, int K)
{
    __shared__ bf16_t As[2 * 128 * 32];   // [kk][row][col0..31], 16 KB
    __shared__ bf16_t Bs[2 * 128 * 32];

    const int t = threadIdx.x;
    const int l = t & 63;
    const int w = t >> 6;
    const int wm = w >> 1, wn = w & 1;
    const int l15 = l & 15, l4 = l >> 4;

    // XCD-chunked swizzle (bijective; our launches have nwg%8==0)
    const int nbx = gridDim.x;
    const int nwg = nbx * gridDim.y;
    int lid = blockIdx.y * nbx + blockIdx.x;
    if ((nwg & 7) == 0) {
        const int cpx = nwg >> 3;
        lid = (lid & 7) * cpx + (lid >> 3);
    }
    const int m0 = (lid / nbx) * 128, n0 = (lid % nbx) * 128;

    floatx4 acc[4][4] = {};

    // staging: 256 threads x 4 chunks x 16B = full [2][128][32] tile.
    const float*  agf[4];
    const bf16_t* agb[4];
    const bf16_t* bg[4];
    bf16_t* al[4];
    bf16_t* bl[4];
#pragma unroll
    for (int i = 0; i < 4; i++) {
        int e = (i * 256 + t) * 8;
        int kk = e >> 12;
        int row = (e & 4095) >> 5;
        int col = kk * 32 + (e & 31);
        int ra = m0 + row; if (ra > M - 1) ra = M - 1;
        if (AF32) agf[i] = (const float*)Av + (size_t)ra * K + col;
        else      agb[i] = (const bf16_t*)Av + (size_t)ra * K + col;
        bg[i] = B + (size_t)(n0 + row) * K + col;
        al[i] = &As[e];
        bl[i] = &Bs[e];
    }

    for (int k0 = 0; k0 < K; k0 += 64) {
#pragma unroll
        for (int i = 0; i < 4; i++) {
            if (AF32) stage_cvt8(agf[i] + k0, al[i]);
            else      gload_lds16(agb[i] + k0, al[i]);
            gload_lds16(bg[i] + k0, bl[i]);
        }
        __syncthreads();

#pragma unroll
        for (int kk = 0; kk < 2; kk++) {
            bf16x8 af[4], bfr[4];
#pragma unroll
            for (int i = 0; i < 4; i++)
                af[i] = *(const bf16x8*)&As[kk * 4096 + (wm * 64 + i * 16 + l15) * 32 + l4 * 8];
#pragma unroll
            for (int j = 0; j < 4; j++)
                bfr[j] = *(const bf16x8*)&Bs[kk * 4096 + (wn * 64 + j * 16 + l15) * 32 + l4 * 8];
#pragma unroll
            for (int i = 0; i < 4; i++)
#pragma unroll
                for (int j = 0; j < 4; j++)
                    acc[i][j] = MFMA16(af[i], bfr[j], acc[i][j]);
        }
        __syncthreads();
    }

    // epilogue: C/D layout col=lane&15, row=(lane>>4)*4+reg
#pragma unroll
    for (int i = 0; i < 4; i++)
#pragma unroll
        for (int j = 0; j < 4; j++)
#pragma unroll
            for (int r = 0; r < 4; r++) {
                int row = m0 + wm * 64 + i * 16 + l4 * 4 + r;
                int col = n0 + wn * 64 + j * 16 + l15;
                if (row < M) {
                    if (CF32) ((float*)Cv)[(size_t)row * N + col] = acc[i][j][r];
                    else ((bf16_t*)Cv)[(size_t)row * N + col] = (bf16_t)acc[i][j][r];
                }
            }
}

// ---------------------------------------------------------------------------
// prep: KV-proj from fp32 (blocks 0..79) + wq cvt (80..207) + wo cvt (208..335)
// KV GEMM: C[1232,1024] = cond[1232,768] @ [Wk|Wv][1024,768]^T, bf16 out,
// interleaved row stride 1024. Both sides reg-staged with inline cvt.
// ---------------------------------------------------------------------------
__global__ __launch_bounds__(256) void prep(
    const float* __restrict__ cond, const float* __restrict__ w_k,
    const float* __restrict__ w_v, const float* __restrict__ w_q,
    const float* __restrict__ w_o, bf16_t* __restrict__ KVb,
    bf16_t* __restrict__ Wqb, bf16_t* __restrict__ Wob)
{
    __shared__ bf16_t As[2 * 128 * 32];
    __shared__ bf16_t Bs[2 * 128 * 32];

    const int bid = blockIdx.x;
    const int t = threadIdx.x;

    if (bid >= 80) {   // weight conversions: 128 blocks each, 2048 elems/block
        if (bid < 208) cvt8(w_q, Wqb, (long long)(bid - 80) * 256 + t);
        else           cvt8(w_o, Wob, (long long)(bid - 208) * 256 + t);
        return;
    }

    // ---- KV-proj block ----
    const int l = t & 63;
    const int w = t >> 6;
    const int wm = w >> 1, wn = w & 1;
    const int l15 = l & 15, l4 = l >> 4;
    const int m0 = (bid >> 3) * 128, n0 = (bid & 7) * 128;
    const int M = 1232, K = 768;

    floatx4 acc[4][4] = {};

    const float* ag[4];
    const float* bg[4];
    bf16_t* al[4];
    bf16_t* bl[4];
#pragma unroll
    for (int i = 0; i < 4; i++) {
        int e = (i * 256 + t) * 8;
        int kk = e >> 12;
        int row = (e & 4095) >> 5;
        int col = kk * 32 + (e & 31);
        int ra = m0 + row; if (ra > M - 1) ra = M - 1;
        ag[i] = cond + (size_t)ra * K + col;
        int rb = n0 + row;   // 0..1023: <512 -> Wk row, else Wv row
        bg[i] = (rb < 512 ? w_k + (size_t)rb * K
                          : w_v + (size_t)(rb - 512) * K) + col;
        al[i] = &As[e];
        bl[i] = &Bs[e];
    }

    for (int k0 = 0; k0 < K; k0 += 64) {
#pragma unroll
        for (int i = 0; i < 4; i++) {
            stage_cvt8(ag[i] + k0, al[i]);
            stage_cvt8(bg[i] + k0, bl[i]);
        }
        __syncthreads();

#pragma unroll
        for (int kk = 0; kk < 2; kk++) {
            bf16x8 af[4], bfr[4];
#pragma unroll
            for (int i = 0; i < 4; i++)
                af[i] = *(const bf16x8*)&As[kk * 4096 + (wm * 64 + i * 16 + l15) * 32 + l4 * 8];
#pragma unroll
            for (int j = 0; j < 4; j++)
                bfr[j] = *(const bf16x8*)&Bs[kk * 4096 + (wn * 64 + j * 16 + l15) * 32 + l4 * 8];
#pragma unroll
            for (int i = 0; i < 4; i++)
#pragma unroll
                for (int j = 0; j < 4; j++)
                    acc[i][j] = MFMA16(af[i], bfr[j], acc[i][j]);
        }
        __syncthreads();
    }

#pragma unroll
    for (int i = 0; i < 4; i++)
#pragma unroll
        for (int j = 0; j < 4; j++)
#pragma unroll
            for (int r = 0; r < 4; r++) {
                int row = m0 + wm * 64 + i * 16 + l4 * 4 + r;
                int col = n0 + wn * 64 + j * 16 + l15;
                if (row < M)
                    KVb[(size_t)row * 1024 + col] = (bf16_t)acc[i][j][r];
            }
}

// ---------------------------------------------------------------------------
// Fused attention, IN-PLACE on QO. 128 q-rows/block, 32 rows/wave.
// K/V interleaved: row j = [K(512) | V(512)], stride 1024.  (unchanged)
// grid: (Lq/128, B*H), block 256.
// ---------------------------------------------------------------------------
#define LK 77
#define KVSTR 1024
#define KSTR 72
#define VSTR 104
#define JP 96

__global__ __launch_bounds__(256) void attn_fused(
    bf16_t* QO,
    const bf16_t* __restrict__ KVg)
{
    __shared__ bf16_t Ks[80 * KSTR];
    __shared__ bf16_t Vs[64 * VSTR];
    __shared__ bf16_t Ps[4 * 32 * VSTR];

    const int t = threadIdx.x;
    const int w = t >> 6, l = t & 63;
    const int l15 = l & 15, l4 = l >> 4;
    const int b = blockIdx.y >> 3, h = blockIdx.y & 7;
    const int q0 = blockIdx.x * 128;

    const bf16_t* qbase =
        QO + ((size_t)(b * 4096 + q0 + w * 32 + l15)) * 512 + h * 64 + l4 * 8;
    bf16x8 aq[2][2];
    aq[0][0] = *(const bf16x8*)qbase;
    aq[0][1] = *(const bf16x8*)(qbase + 32);
    aq[1][0] = *(const bf16x8*)(qbase + 16 * 512);
    aq[1][1] = *(const bf16x8*)(qbase + 16 * 512 + 32);

    const bf16_t* Kg = KVg;
    const bf16_t* Vg = KVg + 512;

    for (int idx = t; idx < LK * 8; idx += 256) {
        int j = idx >> 3, c = (idx & 7) * 8;
        *(uint4*)&Ks[j * KSTR + c] =
            *(const uint4*)&Kg[((size_t)(b * LK + j)) * KVSTR + h * 64 + c];
    }
    for (int idx = t; idx < 3 * KSTR; idx += 256)
        Ks[LK * KSTR + idx] = (bf16_t)0.0f;

    for (int u = t; u < LK * 8; u += 256) {
        int j = u >> 3, d0 = (u & 7) * 8;
        uint4 pk = *(const uint4*)&Vg[((size_t)(b * LK + j)) * KVSTR + h * 64 + d0];
        const bf16_t* pv = (const bf16_t*)&pk;
#pragma unroll
        for (int e = 0; e < 8; e++)
            Vs[(d0 + e) * VSTR + j] = pv[e];
    }
    for (int idx = t; idx < 64 * (JP - LK); idx += 256) {
        int d = idx / (JP - LK), j = LK + idx % (JP - LK);
        Vs[d * VSTR + j] = (bf16_t)0.0f;
    }
    __syncthreads();

    floatx4 s[2][5];
    __builtin_amdgcn_s_setprio(1);
#pragma unroll
    for (int n = 0; n < 5; n++) {
        bf16x8 b0 = *(const bf16x8*)&Ks[(n * 16 + l15) * KSTR + l4 * 8];
        bf16x8 b1 = *(const bf16x8*)&Ks[(n * 16 + l15) * KSTR + 32 + l4 * 8];
#pragma unroll
        for (int mi = 0; mi < 2; mi++) {
            floatx4 z = {0.f, 0.f, 0.f, 0.f};
            z = MFMA16(aq[mi][0], b0, z);
            z = MFMA16(aq[mi][1], b1, z);
            s[mi][n] = z;
        }
    }
    __builtin_amdgcn_s_setprio(0);

    const float scale = 0.125f;
    float p[2][5][4], linv[2][4];
#pragma unroll
    for (int mi = 0; mi < 2; mi++)
#pragma unroll
        for (int r = 0; r < 4; r++) {
            float smax = -1e30f;
#pragma unroll
            for (int n = 0; n < 5; n++) {
                float v = s[mi][n][r] * scale;
                if (n == 4 && (64 + l15) >= LK) v = -1e30f;
                p[mi][n][r] = v;
                smax = fmaxf(smax, v);
            }
#pragma unroll
            for (int off = 1; off < 16; off <<= 1)
                smax = fmaxf(smax, __shfl_xor(smax, off, 64));
            float sum = 0.f;
#pragma unroll
            for (int n = 0; n < 5; n++) {
                float e2 = __expf(p[mi][n][r] - smax);
                p[mi][n][r] = e2;
                sum += e2;
            }
#pragma unroll
            for (int off = 1; off < 16; off <<= 1)
                sum += __shfl_xor(sum, off, 64);
            linv[mi][r] = 1.0f / sum;
        }

    bf16_t* pw = Ps + w * 32 * VSTR;
#pragma unroll
    for (int mi = 0; mi < 2; mi++)
#pragma unroll
        for (int r = 0; r < 4; r++) {
            int row = mi * 16 + l4 * 4 + r;
#pragma unroll
            for (int n = 0; n < 5; n++)
                pw[row * VSTR + n * 16 + l15] = (bf16_t)(p[mi][n][r] * linv[mi][r]);
            pw[row * VSTR + 80 + l15] = (bf16_t)0.0f;
        }
    __syncthreads();

    bf16x8 ap[2][3];
#pragma unroll
    for (int mi = 0; mi < 2; mi++)
#pragma unroll
        for (int ks = 0; ks < 3; ks++)
            ap[mi][ks] = *(const bf16x8*)&pw[(mi * 16 + l15) * VSTR + ks * 32 + l4 * 8];
#pragma unroll
    for (int n2 = 0; n2 < 4; n2++) {
        bf16x8 bv[3];
#pragma unroll
        for (int ks = 0; ks < 3; ks++)
            bv[ks] = *(const bf16x8*)&Vs[(n2 * 16 + l15) * VSTR + ks * 32 + l4 * 8];
        floatx4 o[2];
        __builtin_amdgcn_s_setprio(1);
#pragma unroll
        for (int mi = 0; mi < 2; mi++) {
            floatx4 z = {0.f, 0.f, 0.f, 0.f};
#pragma unroll
            for (int ks = 0; ks < 3; ks++)
                z = MFMA16(ap[mi][ks], bv[ks], z);
            o[mi] = z;
        }
        __builtin_amdgcn_s_setprio(0);
#pragma unroll
        for (int mi = 0; mi < 2; mi++)
#pragma unroll
            for (int r = 0; r < 4; r++) {
                int q = q0 + w * 32 + mi * 16 + l4 * 4 + r;
                QO[((size_t)(b * 4096 + q)) * 512 + h * 64 + n2 * 16 + l15] =
                    (bf16_t)o[mi][r];
            }
    }
}

// ---------------------------------------------------------------------------
extern "C" void kernel_launch(void* const* d_in, const int* in_sizes, int n_in,
                              void* d_out, int out_size, void* d_ws, size_t ws_size,
                              hipStream_t stream)
{
    const float* x    = (const float*)d_in[0];  // [16,4096,512] fp32
    const float* cond = (const float*)d_in[1];  // [16,77,768]   fp32
    const float* w_q  = (const float*)d_in[2];  // [512,512]     fp32
    const float* w_k  = (const float*)d_in[3];  // [512,768]     fp32
    const float* w_v  = (const float*)d_in[4];  // [512,768]     fp32
    const float* w_o  = (const float*)d_in[5];  // [512,512]     fp32
    float* out = (float*)d_out;                 // [16,4096,512] fp32

    const int Mq  = 16 * 4096;   // 65536
    const int Mkv = 16 * 77;     // 1232

    // workspace (bf16): Q/AO 67.1MB | KV 2.5MB | Wq 0.5MB | Wo 0.5MB ≈ 70.6MB
    bf16_t* Qb  = (bf16_t*)d_ws;
    bf16_t* KVb = Qb  + (size_t)Mq * 512;
    bf16_t* Wqb = KVb + (size_t)Mkv * 1024;
    bf16_t* Wob = Wqb + (size_t)512 * 512;

    // 1. prep: KV-proj from fp32 + wq/wo conversion (one launch)
    prep<<<dim3(336), 256, 0, stream>>>(cond, w_k, w_v, w_q, w_o, KVb, Wqb, Wob);

    // 2. Q-projection: A = x fp32 (inline cvt), B = Wqb
    gemm_bt<true, false><<<dim3(4, Mq / 128), 256, 0, stream>>>(x, Wqb, Qb, Mq, 512, 512);

    // 3. fused attention (Q -> AO in place)
    attn_fused<<<dim3(32, 128), 256, 0, stream>>>(Qb, KVb);

    // 4. O-projection: A = Qb bf16, C = out fp32
    gemm_bt<false, true><<<dim3(4, Mq / 128), 256, 0, stream>>>(Qb, Wob, out, Mq, 512, 512);
}